// Round 1
// baseline (1068.166 us; speedup 1.0000x reference)
//
#include <hip/hip_runtime.h>

typedef float v4f __attribute__((ext_vector_type(4)));
typedef __bf16 v8bf __attribute__((ext_vector_type(8)));
typedef unsigned short us8 __attribute__((ext_vector_type(8)));

#define TLEN 1024
#define BSZ  32
#define SLEN 2048
#define DDIM 512
#define LN_EPS 1e-6f

static __device__ __forceinline__ unsigned short f2bf(float f) {
  unsigned int u = __builtin_bit_cast(unsigned int, f);
  u += 0x7FFFu + ((u >> 16) & 1u);
  return (unsigned short)(u >> 16);
}
static __device__ __forceinline__ float bf2f(unsigned short h) {
  unsigned int u = ((unsigned int)h) << 16;
  return __builtin_bit_cast(float, u);
}
static __device__ __forceinline__ void split1(float f, unsigned short& hi, unsigned short& lo) {
  hi = f2bf(f);
  lo = f2bf(f - bf2f(hi));
}
static __device__ __forceinline__ void split4(const float4 v, ushort4& hi, ushort4& lo) {
  split1(v.x, hi.x, lo.x);
  split1(v.y, hi.y, lo.y);
  split1(v.z, hi.z, lo.z);
  split1(v.w, hi.w, lo.w);
}
static __device__ __forceinline__ ushort4 cvt4(const float4 v) {
  ushort4 o;
  o.x = f2bf(v.x); o.y = f2bf(v.y); o.z = f2bf(v.z); o.w = f2bf(v.w);
  return o;
}

// ---------------------------------------------------------------------------
// values [B][S][D] fp32 -> VT [B][D][S] bf16  (so GEMM3's B operand has
// contiguous k=s per output-column d)
// grid: (S/64, D/64, B), 256 threads
// ---------------------------------------------------------------------------
__launch_bounds__(256, 4)
__global__ void k_transpose_v(const float* __restrict__ vals, unsigned short* __restrict__ VT) {
  __shared__ __align__(16) unsigned short t[64][72];
  const int tid = threadIdx.x;
  const int s0 = blockIdx.x * 64, d0 = blockIdx.y * 64, b = blockIdx.z;
  const int r = tid >> 2;         // 0..63
  const int c = (tid & 3) * 16;   // 0,16,32,48
  const float* src = vals + ((size_t)b * SLEN + s0 + r) * DDIM + d0 + c;
#pragma unroll
  for (int j = 0; j < 4; ++j) {
    float4 v = *(const float4*)(src + j * 4);
    t[r][c + j * 4 + 0] = f2bf(v.x);
    t[r][c + j * 4 + 1] = f2bf(v.y);
    t[r][c + j * 4 + 2] = f2bf(v.z);
    t[r][c + j * 4 + 3] = f2bf(v.w);
  }
  __syncthreads();
  unsigned short* dst = VT + ((size_t)b * DDIM + d0 + r) * SLEN + s0 + c;
#pragma unroll
  for (int j = 0; j < 4; ++j) {
    ushort4 o;
    o.x = t[c + j * 4 + 0][r];
    o.y = t[c + j * 4 + 1][r];
    o.z = t[c + j * 4 + 2][r];
    o.w = t[c + j * 4 + 3][r];
    *(ushort4*)(dst + j * 4) = o;
  }
}

// ---------------------------------------------------------------------------
// GEMM1: x[g=b*T+t][e] = sum_d inp[t][b][d] * W[e][d], split-bf16 (3 MFMA passes)
// tile 128x128, BK=32, 256 threads (2x2 waves, each 64x64 = 4x4 16x16 frags)
// grid: (M/128=256, N/128=4)
// ---------------------------------------------------------------------------
__launch_bounds__(256, 2)
__global__ void k_gemm1(const float* __restrict__ inp, const float* __restrict__ Wm,
                        float* __restrict__ xbuf) {
  __shared__ __align__(16) unsigned short sAh[128 * 40];
  __shared__ __align__(16) unsigned short sAl[128 * 40];
  __shared__ __align__(16) unsigned short sBh[128 * 40];
  __shared__ __align__(16) unsigned short sBl[128 * 40];
  const int tid = threadIdx.x;
  const int lane = tid & 63, wv = tid >> 6;
  const int wm = wv >> 1, wn = wv & 1;
  const int lr = lane & 15, lq = lane >> 4;
  const int g0 = blockIdx.x * 128;
  const int n0 = blockIdx.y * 128;

  const int r = tid >> 1, h = tid & 1;
  const int g = g0 + r;  // row in [B*T] ordering: b = g>>10, t = g & 1023
  const float* aRow = inp + ((size_t)((g & (TLEN - 1)) * BSZ + (g >> 10))) * DDIM + h * 16;
  const float* bRow = Wm + (size_t)(n0 + r) * DDIM + h * 16;
  const int stOff = r * 40 + h * 16;

  v4f acc[4][4];
#pragma unroll
  for (int i = 0; i < 4; ++i)
#pragma unroll
    for (int j = 0; j < 4; ++j) acc[i][j] = (v4f)0.0f;

  for (int k0 = 0; k0 < DDIM; k0 += 32) {
#pragma unroll
    for (int c = 0; c < 4; ++c) {
      float4 va = *(const float4*)(aRow + k0 + c * 4);
      float4 vb = *(const float4*)(bRow + k0 + c * 4);
      ushort4 ah, al, bh, bl;
      split4(va, ah, al);
      split4(vb, bh, bl);
      *(ushort4*)&sAh[stOff + c * 4] = ah;
      *(ushort4*)&sAl[stOff + c * 4] = al;
      *(ushort4*)&sBh[stOff + c * 4] = bh;
      *(ushort4*)&sBl[stOff + c * 4] = bl;
    }
    __syncthreads();
    v8bf aH[4], aL[4], bH[4], bL[4];
#pragma unroll
    for (int mi = 0; mi < 4; ++mi) {
      const int off = (wm * 64 + mi * 16 + lr) * 40 + lq * 8;
      aH[mi] = __builtin_bit_cast(v8bf, *(const us8*)&sAh[off]);
      aL[mi] = __builtin_bit_cast(v8bf, *(const us8*)&sAl[off]);
    }
#pragma unroll
    for (int ni = 0; ni < 4; ++ni) {
      const int off = (wn * 64 + ni * 16 + lr) * 40 + lq * 8;
      bH[ni] = __builtin_bit_cast(v8bf, *(const us8*)&sBh[off]);
      bL[ni] = __builtin_bit_cast(v8bf, *(const us8*)&sBl[off]);
    }
#pragma unroll
    for (int mi = 0; mi < 4; ++mi)
#pragma unroll
      for (int ni = 0; ni < 4; ++ni) {
        acc[mi][ni] = __builtin_amdgcn_mfma_f32_16x16x32_bf16(aH[mi], bH[ni], acc[mi][ni], 0, 0, 0);
        acc[mi][ni] = __builtin_amdgcn_mfma_f32_16x16x32_bf16(aL[mi], bH[ni], acc[mi][ni], 0, 0, 0);
        acc[mi][ni] = __builtin_amdgcn_mfma_f32_16x16x32_bf16(aH[mi], bL[ni], acc[mi][ni], 0, 0, 0);
      }
    __syncthreads();
  }
#pragma unroll
  for (int mi = 0; mi < 4; ++mi) {
    const int row = g0 + wm * 64 + mi * 16 + lq * 4;
#pragma unroll
    for (int ni = 0; ni < 4; ++ni) {
      const int col = n0 + wn * 64 + ni * 16 + lr;
#pragma unroll
      for (int j = 0; j < 4; ++j)
        xbuf[(size_t)(row + j) * DDIM + col] = acc[mi][ni][j];
    }
  }
}

// ---------------------------------------------------------------------------
// LayerNorm over D=512, one wave per row; writes split-bf16 targetT to ws
// grid: 32768/4 = 8192 blocks, 256 threads
// ---------------------------------------------------------------------------
__launch_bounds__(256, 4)
__global__ void k_ln(const float* __restrict__ x, const float* __restrict__ gma,
                     const float* __restrict__ bta,
                     unsigned short* __restrict__ tH, unsigned short* __restrict__ tL) {
  const int lane = threadIdx.x & 63;
  const int row = blockIdx.x * 4 + (threadIdx.x >> 6);
  const float* xr = x + (size_t)row * DDIM + lane * 8;
  float4 v0 = *(const float4*)xr;
  float4 v1 = *(const float4*)(xr + 4);
  float s = v0.x + v0.y + v0.z + v0.w + v1.x + v1.y + v1.z + v1.w;
#pragma unroll
  for (int o = 1; o < 64; o <<= 1) s += __shfl_xor(s, o, 64);
  const float mu = s * (1.0f / DDIM);
  const float d0 = v0.x - mu, d1 = v0.y - mu, d2 = v0.z - mu, d3 = v0.w - mu;
  const float d4 = v1.x - mu, d5 = v1.y - mu, d6 = v1.z - mu, d7 = v1.w - mu;
  float q = d0 * d0 + d1 * d1 + d2 * d2 + d3 * d3 + d4 * d4 + d5 * d5 + d6 * d6 + d7 * d7;
#pragma unroll
  for (int o = 1; o < 64; o <<= 1) q += __shfl_xor(q, o, 64);
  const float rs = rsqrtf(q * (1.0f / DDIM) + LN_EPS);
  const float4 ga = *(const float4*)(gma + lane * 8);
  const float4 gb = *(const float4*)(gma + lane * 8 + 4);
  const float4 ba = *(const float4*)(bta + lane * 8);
  const float4 bb = *(const float4*)(bta + lane * 8 + 4);
  const float y0 = ga.x * d0 * rs + ba.x;
  const float y1 = ga.y * d1 * rs + ba.y;
  const float y2 = ga.z * d2 * rs + ba.z;
  const float y3 = ga.w * d3 * rs + ba.w;
  const float y4 = gb.x * d4 * rs + bb.x;
  const float y5 = gb.y * d5 * rs + bb.y;
  const float y6 = gb.z * d6 * rs + bb.z;
  const float y7 = gb.w * d7 * rs + bb.w;
  ushort4 h0, l0, h1, l1;
  split1(y0, h0.x, l0.x); split1(y1, h0.y, l0.y);
  split1(y2, h0.z, l0.z); split1(y3, h0.w, l0.w);
  split1(y4, h1.x, l1.x); split1(y5, h1.y, l1.y);
  split1(y6, h1.z, l1.z); split1(y7, h1.w, l1.w);
  unsigned short* oH = tH + (size_t)row * DDIM + lane * 8;
  unsigned short* oL = tL + (size_t)row * DDIM + lane * 8;
  *(ushort4*)oH = h0;
  *(ushort4*)(oH + 4) = h1;
  *(ushort4*)oL = l0;
  *(ushort4*)(oL + 4) = l1;
}

// ---------------------------------------------------------------------------
// GEMM2: scores[b][t][s] = sum_d tgt[b*T+t][d] * ctx[b][s][d]
// A = presplit bf16 (tH/tL), B = fp32 context reg-split. 3 MFMA passes.
// grid: (T/128=8, S/128=16, B=32)
// ---------------------------------------------------------------------------
__launch_bounds__(256, 2)
__global__ void k_gemm2(const unsigned short* __restrict__ tH,
                        const unsigned short* __restrict__ tL,
                        const float* __restrict__ ctx,
                        float* __restrict__ attn) {
  __shared__ __align__(16) unsigned short sAh[128 * 40];
  __shared__ __align__(16) unsigned short sAl[128 * 40];
  __shared__ __align__(16) unsigned short sBh[128 * 40];
  __shared__ __align__(16) unsigned short sBl[128 * 40];
  const int tid = threadIdx.x;
  const int lane = tid & 63, wv = tid >> 6;
  const int wm = wv >> 1, wn = wv & 1;
  const int lr = lane & 15, lq = lane >> 4;
  const int b = blockIdx.z;
  const int t0 = blockIdx.x * 128;
  const int s0 = blockIdx.y * 128;

  const int r = tid >> 1, h = tid & 1;
  const unsigned short* aHrow = tH + ((size_t)(b * TLEN + t0 + r)) * DDIM + h * 16;
  const unsigned short* aLrow = tL + ((size_t)(b * TLEN + t0 + r)) * DDIM + h * 16;
  const float* bRow = ctx + ((size_t)b * SLEN + s0 + r) * DDIM + h * 16;
  const int stOff = r * 40 + h * 16;

  v4f acc[4][4];
#pragma unroll
  for (int i = 0; i < 4; ++i)
#pragma unroll
    for (int j = 0; j < 4; ++j) acc[i][j] = (v4f)0.0f;

  for (int k0 = 0; k0 < DDIM; k0 += 32) {
    us8 a0 = *(const us8*)(aHrow + k0);
    us8 a1 = *(const us8*)(aHrow + k0 + 8);
    us8 a2 = *(const us8*)(aLrow + k0);
    us8 a3 = *(const us8*)(aLrow + k0 + 8);
    *(us8*)&sAh[stOff] = a0;
    *(us8*)&sAh[stOff + 8] = a1;
    *(us8*)&sAl[stOff] = a2;
    *(us8*)&sAl[stOff + 8] = a3;
#pragma unroll
    for (int c = 0; c < 4; ++c) {
      float4 vb = *(const float4*)(bRow + k0 + c * 4);
      ushort4 bh, bl;
      split4(vb, bh, bl);
      *(ushort4*)&sBh[stOff + c * 4] = bh;
      *(ushort4*)&sBl[stOff + c * 4] = bl;
    }
    __syncthreads();
    v8bf aH[4], aL[4], bH[4], bL[4];
#pragma unroll
    for (int mi = 0; mi < 4; ++mi) {
      const int off = (wm * 64 + mi * 16 + lr) * 40 + lq * 8;
      aH[mi] = __builtin_bit_cast(v8bf, *(const us8*)&sAh[off]);
      aL[mi] = __builtin_bit_cast(v8bf, *(const us8*)&sAl[off]);
    }
#pragma unroll
    for (int ni = 0; ni < 4; ++ni) {
      const int off = (wn * 64 + ni * 16 + lr) * 40 + lq * 8;
      bH[ni] = __builtin_bit_cast(v8bf, *(const us8*)&sBh[off]);
      bL[ni] = __builtin_bit_cast(v8bf, *(const us8*)&sBl[off]);
    }
#pragma unroll
    for (int mi = 0; mi < 4; ++mi)
#pragma unroll
      for (int ni = 0; ni < 4; ++ni) {
        acc[mi][ni] = __builtin_amdgcn_mfma_f32_16x16x32_bf16(aH[mi], bH[ni], acc[mi][ni], 0, 0, 0);
        acc[mi][ni] = __builtin_amdgcn_mfma_f32_16x16x32_bf16(aL[mi], bH[ni], acc[mi][ni], 0, 0, 0);
        acc[mi][ni] = __builtin_amdgcn_mfma_f32_16x16x32_bf16(aH[mi], bL[ni], acc[mi][ni], 0, 0, 0);
      }
    __syncthreads();
  }
#pragma unroll
  for (int mi = 0; mi < 4; ++mi) {
    const int trow = t0 + wm * 64 + mi * 16 + lq * 4;
#pragma unroll
    for (int ni = 0; ni < 4; ++ni) {
      const int col = s0 + wn * 64 + ni * 16 + lr;
#pragma unroll
      for (int j = 0; j < 4; ++j)
        attn[((size_t)(b * TLEN + trow + j)) * SLEN + col] = acc[mi][ni][j];
    }
  }
}

// ---------------------------------------------------------------------------
// softmax over S=2048, in place, one block per row
// ---------------------------------------------------------------------------
__launch_bounds__(256, 4)
__global__ void k_softmax(float* __restrict__ attn) {
  __shared__ float red[4];
  const int tid = threadIdx.x;
  const int lane = tid & 63, wv = tid >> 6;
  float* p = attn + (size_t)blockIdx.x * SLEN + tid * 8;
  float4 a = *(const float4*)p;
  float4 b = *(const float4*)(p + 4);
  float m = fmaxf(fmaxf(fmaxf(a.x, a.y), fmaxf(a.z, a.w)),
                  fmaxf(fmaxf(b.x, b.y), fmaxf(b.z, b.w)));
#pragma unroll
  for (int o = 1; o < 64; o <<= 1) m = fmaxf(m, __shfl_xor(m, o, 64));
  if (lane == 0) red[wv] = m;
  __syncthreads();
  m = fmaxf(fmaxf(red[0], red[1]), fmaxf(red[2], red[3]));
  __syncthreads();
  a.x = __expf(a.x - m); a.y = __expf(a.y - m);
  a.z = __expf(a.z - m); a.w = __expf(a.w - m);
  b.x = __expf(b.x - m); b.y = __expf(b.y - m);
  b.z = __expf(b.z - m); b.w = __expf(b.w - m);
  float s = a.x + a.y + a.z + a.w + b.x + b.y + b.z + b.w;
#pragma unroll
  for (int o = 1; o < 64; o <<= 1) s += __shfl_xor(s, o, 64);
  if (lane == 0) red[wv] = s;
  __syncthreads();
  s = red[0] + red[1] + red[2] + red[3];
  const float inv = 1.0f / s;
  a.x *= inv; a.y *= inv; a.z *= inv; a.w *= inv;
  b.x *= inv; b.y *= inv; b.z *= inv; b.w *= inv;
  *(float4*)p = a;
  *(float4*)(p + 4) = b;
}

// ---------------------------------------------------------------------------
// GEMM3: wc[t][b][d] = sum_s attn[b*T+t][s] * values[b][s][d]
// A = attn fp32 -> bf16 reg-staged, B = VT bf16. Single MFMA pass.
// grid: (T/128=8, D/128=4, B=32)
// ---------------------------------------------------------------------------
__launch_bounds__(256, 2)
__global__ void k_gemm3(const float* __restrict__ attn,
                        const unsigned short* __restrict__ VT,
                        float* __restrict__ out) {
  __shared__ __align__(16) unsigned short sA[128 * 40];
  __shared__ __align__(16) unsigned short sB[128 * 40];
  const int tid = threadIdx.x;
  const int lane = tid & 63, wv = tid >> 6;
  const int wm = wv >> 1, wn = wv & 1;
  const int lr = lane & 15, lq = lane >> 4;
  const int b = blockIdx.z;
  const int t0 = blockIdx.x * 128;
  const int n0 = blockIdx.y * 128;

  const int r = tid >> 1, h = tid & 1;
  const float* aRow = attn + ((size_t)(b * TLEN + t0 + r)) * SLEN + h * 16;
  const unsigned short* bRow = VT + ((size_t)(b * DDIM + n0 + r)) * SLEN + h * 16;
  const int stOff = r * 40 + h * 16;

  v4f acc[4][4];
#pragma unroll
  for (int i = 0; i < 4; ++i)
#pragma unroll
    for (int j = 0; j < 4; ++j) acc[i][j] = (v4f)0.0f;

  for (int k0 = 0; k0 < SLEN; k0 += 32) {
#pragma unroll
    for (int c = 0; c < 4; ++c) {
      float4 va = *(const float4*)(aRow + k0 + c * 4);
      *(ushort4*)&sA[stOff + c * 4] = cvt4(va);
    }
    us8 b0 = *(const us8*)(bRow + k0);
    us8 b1 = *(const us8*)(bRow + k0 + 8);
    *(us8*)&sB[stOff] = b0;
    *(us8*)&sB[stOff + 8] = b1;
    __syncthreads();
    v8bf aF[4], bF[4];
#pragma unroll
    for (int mi = 0; mi < 4; ++mi) {
      const int off = (wm * 64 + mi * 16 + lr) * 40 + lq * 8;
      aF[mi] = __builtin_bit_cast(v8bf, *(const us8*)&sA[off]);
    }
#pragma unroll
    for (int ni = 0; ni < 4; ++ni) {
      const int off = (wn * 64 + ni * 16 + lr) * 40 + lq * 8;
      bF[ni] = __builtin_bit_cast(v8bf, *(const us8*)&sB[off]);
    }
#pragma unroll
    for (int mi = 0; mi < 4; ++mi)
#pragma unroll
      for (int ni = 0; ni < 4; ++ni)
        acc[mi][ni] = __builtin_amdgcn_mfma_f32_16x16x32_bf16(aF[mi], bF[ni], acc[mi][ni], 0, 0, 0);
    __syncthreads();
  }
#pragma unroll
  for (int mi = 0; mi < 4; ++mi) {
    const int trow = t0 + wm * 64 + mi * 16 + lq * 4;
#pragma unroll
    for (int ni = 0; ni < 4; ++ni) {
      const int col = n0 + wn * 64 + ni * 16 + lr;
#pragma unroll
      for (int j = 0; j < 4; ++j)
        out[((size_t)(trow + j) * BSZ + b) * DDIM + col] = acc[mi][ni][j];
    }
  }
}

// ---------------------------------------------------------------------------
extern "C" void kernel_launch(void* const* d_in, const int* in_sizes, int n_in,
                              void* d_out, int out_size, void* d_ws, size_t ws_size,
                              hipStream_t stream) {
  const float* inp = (const float*)d_in[0];   // [T,B,D]
  const float* ctx = (const float*)d_in[1];   // [B,S,D]
  const float* vals = (const float*)d_in[2];  // [B,S,D]
  const float* Wm = (const float*)d_in[3];    // [D,D]
  const float* gma = (const float*)d_in[4];   // [D]
  const float* bta = (const float*)d_in[5];   // [D]

  float* out = (float*)d_out;
  float* wc = out;                      // [T,B,D]  = 16777216 floats
  float* attn = out + 16777216;         // [B*T,S]  = 67108864 floats
  float* xbuf = attn;                   // scratch: x [B*T,D] lives in attn region
                                        // until k_ln consumes it (before k_gemm2)

  // workspace: tgt hi/lo (2 x 16.78M ushort) + VT (33.55M ushort) = 134.2 MB
  unsigned short* tH = (unsigned short*)d_ws;
  unsigned short* tL = tH + 16777216;
  unsigned short* VT = tL + 16777216;

  k_transpose_v<<<dim3(SLEN / 64, DDIM / 64, BSZ), 256, 0, stream>>>(vals, VT);
  k_gemm1<<<dim3((BSZ * TLEN) / 128, DDIM / 128), 256, 0, stream>>>(inp, Wm, xbuf);
  k_ln<<<dim3((BSZ * TLEN) / 4), 256, 0, stream>>>(xbuf, gma, bta, tH, tL);
  k_gemm2<<<dim3(TLEN / 128, SLEN / 128, BSZ), 256, 0, stream>>>(tH, tL, ctx, attn);
  k_softmax<<<dim3(BSZ * TLEN), 256, 0, stream>>>(attn);
  k_gemm3<<<dim3(TLEN / 128, DDIM / 128, BSZ), 256, 0, stream>>>(attn, VT, wc);
}